// Round 1
// baseline (704.261 us; speedup 1.0000x reference)
//
#include <hip/hip_runtime.h>

#define VQ_B 32
#define VQ_D 64
#define VQ_L 4096
#define VQ_N 1024
#define VQ_R (VQ_B * VQ_L)            /* 131072 rows */
#define VQ_ZQ ((size_t)VQ_R * VQ_D)   /* 8388608 z_q elements */
#define MAIN_BLOCK 256
#define MAIN_GRID (VQ_R / MAIN_BLOCK) /* 512 */

// numpy pairwise_sum (n=64, contiguous) over fl(v[i]^2):
// 8 accumulators, sequential blocks of 8, then ((r0+r1)+(r2+r3))+((r4+r5)+(r6+r7)).
// asm barrier: the square MUST be rounded before the add (no fma contraction),
// to match numpy's elementwise x*x temp followed by pairwise sum.
__device__ __forceinline__ float np_pairwise64_sq(const float* v) {
    float r[8];
#pragma unroll
    for (int j = 0; j < 8; ++j) {
        float s = v[j] * v[j];
        asm volatile("" : "+v"(s));
        r[j] = s;
    }
#pragma unroll
    for (int i = 8; i < 64; i += 8) {
#pragma unroll
        for (int j = 0; j < 8; ++j) {
            float s = v[i + j] * v[i + j];
            asm volatile("" : "+v"(s));
            r[j] += s;
        }
    }
    return ((r[0] + r[1]) + (r[2] + r[3])) + ((r[4] + r[5]) + (r[6] + r[7]));
}

__global__ void vq_norme(const float* __restrict__ emb, float* __restrict__ nE) {
    const int c = blockIdx.x * blockDim.x + threadIdx.x;
    if (c >= VQ_N) return;
    const float* ec = emb + (c << 6);
    float ev[VQ_D];
#pragma unroll
    for (int d = 0; d < VQ_D; ++d) ev[d] = ec[d];
    nE[c] = np_pairwise64_sq(ev);
}

__global__ __launch_bounds__(MAIN_BLOCK) void vq_main(
    const float* __restrict__ z, const float* __restrict__ emb,
    const float* __restrict__ nE, float* __restrict__ out,
    float* __restrict__ partials)
{
    const int r = blockIdx.x * MAIN_BLOCK + threadIdx.x;
    const int b = r >> 12;            /* L = 4096 */
    const int l = r & (VQ_L - 1);
    const float* zp = z + ((size_t)b << 18) + l;  /* z[b, d, l], stride L over d */

    float zv[VQ_D];
#pragma unroll
    for (int d = 0; d < VQ_D; ++d) zv[d] = zp[(size_t)d << 12];

    const float szz = np_pairwise64_sq(zv);  /* == np.sum(z_flat*z_flat, axis=1) */

    float best = __builtin_inff();
    int bc = 0;
#pragma unroll 2
    for (int c = 0; c < VQ_N; ++c) {
        const float* __restrict__ ec = emb + (c << 6);  /* wave-uniform -> s_load */
        float acc = 0.0f;
        // OpenBLAS sgemm microkernel replica: single accumulator,
        // ascending-k sequential fp32 FMA chain.
#pragma unroll
        for (int k = 0; k < VQ_D; ++k)
            acc = __builtin_fmaf(zv[k], ec[k], acc);
        // fl(fl(szz - fl(2*acc)) + nE[c]); 2*acc is exact, contraction-safe.
        const float dist = (szz - 2.0f * acc) + nE[c];
        if (dist < best) { best = dist; bc = c; }  /* strict <: first index on ties */
    }

    /* z_q[b, d, l] = emb[bc, d]; coalesced across lanes (consecutive l) */
    const float* __restrict__ eb = emb + (bc << 6);
    float lsum = 0.0f;
#pragma unroll
    for (int d = 0; d < VQ_D; ++d) {
        const float q = eb[d];
        out[((size_t)b << 18) + ((size_t)d << 12) + l] = q;
        const float df = q - zv[d];
        lsum = __builtin_fmaf(df, df, lsum);
    }
    out[VQ_ZQ + 1 + (size_t)r] = (float)bc;  /* codes, as float32 */

    /* deterministic per-block loss partial: wave shuffle-reduce then LDS */
#pragma unroll
    for (int off = 32; off > 0; off >>= 1)
        lsum += __shfl_down(lsum, off, 64);
    __shared__ float wsum[MAIN_BLOCK / 64];
    const int lane = threadIdx.x & 63;
    const int wid = threadIdx.x >> 6;
    if (lane == 0) wsum[wid] = lsum;
    __syncthreads();
    if (threadIdx.x == 0)
        partials[blockIdx.x] = (wsum[0] + wsum[1]) + (wsum[2] + wsum[3]);
}

__global__ void vq_final(const float* __restrict__ partials, float* __restrict__ out) {
    if (threadIdx.x == 0 && blockIdx.x == 0) {
        float s = 0.0f;
        for (int i = 0; i < MAIN_GRID; ++i) s += partials[i];
        const float mse = s / (float)VQ_ZQ;
        out[VQ_ZQ] = mse + 0.25f * mse;  /* vq_loss + 0.25*commitment, identical terms */
    }
}

extern "C" void kernel_launch(void* const* d_in, const int* in_sizes, int n_in,
                              void* d_out, int out_size, void* d_ws, size_t ws_size,
                              hipStream_t stream) {
    const float* z   = (const float*)d_in[0];
    const float* emb = (const float*)d_in[1];
    float* out = (float*)d_out;
    float* nE = (float*)d_ws;          /* 1024 floats */
    float* partials = nE + VQ_N;       /* 512 floats  */

    vq_norme<<<dim3(VQ_N / 256), dim3(256), 0, stream>>>(emb, nE);
    vq_main<<<dim3(MAIN_GRID), dim3(MAIN_BLOCK), 0, stream>>>(z, emb, nE, out, partials);
    vq_final<<<dim3(1), dim3(64), 0, stream>>>(partials, out);
}

// Round 2
// 333.225 us; speedup vs baseline: 2.1135x; 2.1135x over previous
//
#include <hip/hip_runtime.h>

#define VQ_B 32
#define VQ_D 64
#define VQ_L 4096
#define VQ_N 1024
#define VQ_R (VQ_B * VQ_L)            /* 131072 rows */
#define VQ_ZQ ((size_t)VQ_R * VQ_D)   /* 8388608 z_q elements */
#define MAIN_BLOCK 256
#define MAIN_GRID (VQ_R / MAIN_BLOCK) /* 512 */
#define NSEG 4
#define SEG_C (VQ_N / NSEG)           /* 256 codes per segment */

// numpy pairwise_sum (n=64, contiguous) over fl(v[i]^2):
// 8 accumulators, sequential blocks of 8, then ((r0+r1)+(r2+r3))+((r4+r5)+(r6+r7)).
// asm barrier: square must be rounded before the add (no fma contraction).
__device__ __forceinline__ float np_pairwise64_sq(const float* v) {
    float r[8];
#pragma unroll
    for (int j = 0; j < 8; ++j) {
        float s = v[j] * v[j];
        asm volatile("" : "+v"(s));
        r[j] = s;
    }
#pragma unroll
    for (int i = 8; i < 64; i += 8) {
#pragma unroll
        for (int j = 0; j < 8; ++j) {
            float s = v[i + j] * v[i + j];
            asm volatile("" : "+v"(s));
            r[j] += s;
        }
    }
    return ((r[0] + r[1]) + (r[2] + r[3])) + ((r[4] + r[5]) + (r[6] + r[7]));
}

__global__ void vq_norme(const float* __restrict__ emb, float* __restrict__ nE) {
    const int c = blockIdx.x * blockDim.x + threadIdx.x;
    if (c >= VQ_N) return;
    const float* ec = emb + (c << 6);
    float ev[VQ_D];
#pragma unroll
    for (int d = 0; d < VQ_D; ++d) ev[d] = ec[d];
    nE[c] = np_pairwise64_sq(ev);
}

/* Segment distance kernel: blockIdx.y = code segment. Candidates to ws. */
__global__ __launch_bounds__(MAIN_BLOCK, 4) void vq_dist(
    const float* __restrict__ z, const float* __restrict__ emb,
    const float* __restrict__ nE, float2* __restrict__ cand)
{
    const int r = blockIdx.x * MAIN_BLOCK + threadIdx.x;
    const int seg = blockIdx.y;
    const int b = r >> 12;
    const int l = r & (VQ_L - 1);
    const float* zp = z + ((size_t)b << 18) + l;

    float zv[VQ_D];
#pragma unroll
    for (int d = 0; d < VQ_D; ++d) zv[d] = zp[(size_t)d << 12];

    const float szz = np_pairwise64_sq(zv);  /* bitwise identical per segment */

    const int c0 = seg * SEG_C;
    float best = __builtin_inff();
    int bc = c0;
#pragma unroll 2
    for (int cc = 0; cc < SEG_C; ++cc) {
        const int c = c0 + cc;
        const float* __restrict__ ec = emb + (c << 6);  /* wave-uniform -> s_load */
        float acc = 0.0f;
#pragma unroll
        for (int k = 0; k < VQ_D; ++k)
            acc = __builtin_fmaf(zv[k], ec[k], acc);    /* OpenBLAS sdot chain */
        const float dist = (szz - 2.0f * acc) + nE[c];
        if (dist < best) { best = dist; bc = c; }       /* strict <: first index */
    }
    cand[(size_t)seg * VQ_R + r] = make_float2(best, (float)bc);
}

/* Merge 4 candidates, gather, write z_q + codes, loss partials. */
__global__ __launch_bounds__(MAIN_BLOCK) void vq_epilogue(
    const float* __restrict__ z, const float* __restrict__ emb,
    const float2* __restrict__ cand, float* __restrict__ out,
    float* __restrict__ partials)
{
    const int r = blockIdx.x * MAIN_BLOCK + threadIdx.x;
    const int b = r >> 12;
    const int l = r & (VQ_L - 1);

    float best = __builtin_inff();
    int bc = 0;
#pragma unroll
    for (int seg = 0; seg < NSEG; ++seg) {              /* ascending: ties -> first */
        const float2 cd = cand[(size_t)seg * VQ_R + r];
        if (cd.x < best) { best = cd.x; bc = (int)cd.y; }
    }

    const float* zp = z + ((size_t)b << 18) + l;
    const float* __restrict__ eb = emb + (bc << 6);
    float lsum = 0.0f;
#pragma unroll
    for (int d = 0; d < VQ_D; ++d) {
        const float q = eb[d];
        const float zd = zp[(size_t)d << 12];
        out[((size_t)b << 18) + ((size_t)d << 12) + l] = q;
        const float df = q - zd;
        lsum = __builtin_fmaf(df, df, lsum);
    }
    out[VQ_ZQ + 1 + (size_t)r] = (float)bc;

#pragma unroll
    for (int off = 32; off > 0; off >>= 1)
        lsum += __shfl_down(lsum, off, 64);
    __shared__ float wsum[MAIN_BLOCK / 64];
    const int lane = threadIdx.x & 63;
    const int wid = threadIdx.x >> 6;
    if (lane == 0) wsum[wid] = lsum;
    __syncthreads();
    if (threadIdx.x == 0)
        partials[blockIdx.x] = (wsum[0] + wsum[1]) + (wsum[2] + wsum[3]);
}

/* Fallback monolithic kernel (used only if ws is too small for candidates). */
__global__ __launch_bounds__(MAIN_BLOCK, 4) void vq_main(
    const float* __restrict__ z, const float* __restrict__ emb,
    const float* __restrict__ nE, float* __restrict__ out,
    float* __restrict__ partials)
{
    const int r = blockIdx.x * MAIN_BLOCK + threadIdx.x;
    const int b = r >> 12;
    const int l = r & (VQ_L - 1);
    const float* zp = z + ((size_t)b << 18) + l;

    float zv[VQ_D];
#pragma unroll
    for (int d = 0; d < VQ_D; ++d) zv[d] = zp[(size_t)d << 12];
    const float szz = np_pairwise64_sq(zv);

    float best = __builtin_inff();
    int bc = 0;
#pragma unroll 2
    for (int c = 0; c < VQ_N; ++c) {
        const float* __restrict__ ec = emb + (c << 6);
        float acc = 0.0f;
#pragma unroll
        for (int k = 0; k < VQ_D; ++k)
            acc = __builtin_fmaf(zv[k], ec[k], acc);
        const float dist = (szz - 2.0f * acc) + nE[c];
        if (dist < best) { best = dist; bc = c; }
    }

    const float* __restrict__ eb = emb + (bc << 6);
    float lsum = 0.0f;
#pragma unroll
    for (int d = 0; d < VQ_D; ++d) {
        const float q = eb[d];
        out[((size_t)b << 18) + ((size_t)d << 12) + l] = q;
        const float df = q - zv[d];
        lsum = __builtin_fmaf(df, df, lsum);
    }
    out[VQ_ZQ + 1 + (size_t)r] = (float)bc;

#pragma unroll
    for (int off = 32; off > 0; off >>= 1)
        lsum += __shfl_down(lsum, off, 64);
    __shared__ float wsum[MAIN_BLOCK / 64];
    const int lane = threadIdx.x & 63;
    const int wid = threadIdx.x >> 6;
    if (lane == 0) wsum[wid] = lsum;
    __syncthreads();
    if (threadIdx.x == 0)
        partials[blockIdx.x] = (wsum[0] + wsum[1]) + (wsum[2] + wsum[3]);
}

__global__ void vq_final(const float* __restrict__ partials, float* __restrict__ out) {
    if (threadIdx.x == 0 && blockIdx.x == 0) {
        float s = 0.0f;
        for (int i = 0; i < MAIN_GRID; ++i) s += partials[i];
        const float mse = s / (float)VQ_ZQ;
        out[VQ_ZQ] = mse + 0.25f * mse;
    }
}

extern "C" void kernel_launch(void* const* d_in, const int* in_sizes, int n_in,
                              void* d_out, int out_size, void* d_ws, size_t ws_size,
                              hipStream_t stream) {
    const float* z   = (const float*)d_in[0];
    const float* emb = (const float*)d_in[1];
    float* out = (float*)d_out;
    float* nE = (float*)d_ws;                       /* 1024 f  @ 0      */
    float* partials = nE + VQ_N;                    /* 512 f   @ 4096B  */
    float2* cand = (float2*)(partials + MAIN_GRID); /* 4*R f2  @ 6144B  */

    const size_t need = (size_t)(VQ_N + MAIN_GRID) * 4 + (size_t)NSEG * VQ_R * 8;

    vq_norme<<<dim3(VQ_N / 256), dim3(256), 0, stream>>>(emb, nE);
    if (ws_size >= need) {
        vq_dist<<<dim3(MAIN_GRID, NSEG), dim3(MAIN_BLOCK), 0, stream>>>(z, emb, nE, cand);
        vq_epilogue<<<dim3(MAIN_GRID), dim3(MAIN_BLOCK), 0, stream>>>(z, emb, cand, out, partials);
    } else {
        vq_main<<<dim3(MAIN_GRID), dim3(MAIN_BLOCK), 0, stream>>>(z, emb, nE, out, partials);
    }
    vq_final<<<dim3(1), dim3(64), 0, stream>>>(partials, out);
}

// Round 3
// 331.744 us; speedup vs baseline: 2.1229x; 1.0045x over previous
//
#include <hip/hip_runtime.h>

#define VQ_B 32
#define VQ_D 64
#define VQ_L 4096
#define VQ_N 1024
#define VQ_R (VQ_B * VQ_L)            /* 131072 rows */
#define VQ_ZQ ((size_t)VQ_R * VQ_D)   /* 8388608 z_q elements */
#define MAIN_BLOCK 256
#define MAIN_GRID (VQ_R / MAIN_BLOCK) /* 512 */
#define NSEG 4
#define SEG_C (VQ_N / NSEG)           /* 256 codes per segment */

typedef __attribute__((ext_vector_type(16))) float f32x16;

/* zv element i (0..63) out of four named 16-wide vector registers.
   All uses are after full unroll -> compile-time-constant subscripts. */
#define ZVE(i) ((i) < 16 ? zvA[(i) & 15] : (i) < 32 ? zvB[(i) & 15] \
               : (i) < 48 ? zvC[(i) & 15] : zvD[(i) & 15])

/* fl(x*x) rounded BEFORE any add (numpy elementwise temp; no fma fusion). */
#define SQB(x) ({ float s_ = (x) * (x); asm volatile("" : "+v"(s_)); s_; })

/* numpy pairwise_sum (n=64 contiguous) of squares:
   r[j] = sum_i v[8i+j]^2 sequentially, then ((r0+r1)+(r2+r3))+((r4+r5)+(r6+r7)). */
#define NP_PAIRWISE64_SQ(dst)                                                  \
    do {                                                                       \
        float r0 = SQB(ZVE(0)), r1 = SQB(ZVE(1)), r2 = SQB(ZVE(2)),            \
              r3 = SQB(ZVE(3)), r4 = SQB(ZVE(4)), r5 = SQB(ZVE(5)),            \
              r6 = SQB(ZVE(6)), r7 = SQB(ZVE(7));                              \
        _Pragma("unroll")                                                      \
        for (int i_ = 1; i_ < 8; ++i_) {                                       \
            r0 += SQB(ZVE(8 * i_ + 0)); r1 += SQB(ZVE(8 * i_ + 1));            \
            r2 += SQB(ZVE(8 * i_ + 2)); r3 += SQB(ZVE(8 * i_ + 3));            \
            r4 += SQB(ZVE(8 * i_ + 4)); r5 += SQB(ZVE(8 * i_ + 5));            \
            r6 += SQB(ZVE(8 * i_ + 6)); r7 += SQB(ZVE(8 * i_ + 7));            \
        }                                                                      \
        dst = ((r0 + r1) + (r2 + r3)) + ((r4 + r5) + (r6 + r7));               \
    } while (0)

__global__ void vq_norme(const float* __restrict__ emb, float* __restrict__ nE) {
    const int c = blockIdx.x * blockDim.x + threadIdx.x;
    if (c >= VQ_N) return;
    const float* ec = emb + (c << 6);
    f32x16 zvA, zvB, zvC, zvD;
#pragma unroll
    for (int d = 0; d < 16; ++d) {
        zvA[d] = ec[d];
        zvB[d] = ec[d + 16];
        zvC[d] = ec[d + 32];
        zvD[d] = ec[d + 48];
    }
    float s;
    NP_PAIRWISE64_SQ(s);
    nE[c] = s;
}

/* Segment distance kernel: blockIdx.y = code segment. Candidates to ws. */
__global__ __launch_bounds__(MAIN_BLOCK, 4) void vq_dist(
    const float* __restrict__ z, const float* __restrict__ emb,
    const float* __restrict__ nE, float2* __restrict__ cand)
{
    const int r = blockIdx.x * MAIN_BLOCK + threadIdx.x;
    const int seg = blockIdx.y;
    const int b = r >> 12;
    const int l = r & (VQ_L - 1);
    const float* zp = z + ((size_t)b << 18) + l;   /* z[b, d, l], stride L over d */

    f32x16 zvA, zvB, zvC, zvD;
#pragma unroll
    for (int d = 0; d < 16; ++d) {
        zvA[d] = zp[(size_t)d << 12];
        zvB[d] = zp[(size_t)(d + 16) << 12];
        zvC[d] = zp[(size_t)(d + 32) << 12];
        zvD[d] = zp[(size_t)(d + 48) << 12];
    }

    float szz;
    NP_PAIRWISE64_SQ(szz);   /* bitwise identical across segments */

    const int c0 = seg * SEG_C;
    float best = __builtin_inff();
    int bc = c0;
#pragma unroll 2
    for (int cc = 0; cc < SEG_C; ++cc) {
        const int c = c0 + cc;
        const float* __restrict__ ec = emb + (c << 6);  /* wave-uniform -> s_load */
        float acc = 0.0f;
#pragma unroll
        for (int k = 0; k < VQ_D; ++k)
            acc = __builtin_fmaf(ZVE(k), ec[k], acc);   /* OpenBLAS sdot chain */
        const float dist = (szz - 2.0f * acc) + nE[c];
        if (dist < best) { best = dist; bc = c; }       /* strict <: first index */
    }
    cand[(size_t)seg * VQ_R + r] = make_float2(best, (float)bc);
}

/* Merge 4 candidates, gather, write z_q + codes, loss partials. */
__global__ __launch_bounds__(MAIN_BLOCK) void vq_epilogue(
    const float* __restrict__ z, const float* __restrict__ emb,
    const float2* __restrict__ cand, float* __restrict__ out,
    float* __restrict__ partials)
{
    const int r = blockIdx.x * MAIN_BLOCK + threadIdx.x;
    const int b = r >> 12;
    const int l = r & (VQ_L - 1);

    float best = __builtin_inff();
    int bc = 0;
#pragma unroll
    for (int seg = 0; seg < NSEG; ++seg) {              /* ascending: ties -> first */
        const float2 cd = cand[(size_t)seg * VQ_R + r];
        if (cd.x < best) { best = cd.x; bc = (int)cd.y; }
    }

    const float* zp = z + ((size_t)b << 18) + l;
    const float* __restrict__ eb = emb + (bc << 6);
    float lsum = 0.0f;
#pragma unroll
    for (int d = 0; d < VQ_D; ++d) {
        const float q = eb[d];
        const float zd = zp[(size_t)d << 12];
        out[((size_t)b << 18) + ((size_t)d << 12) + l] = q;
        const float df = q - zd;
        lsum = __builtin_fmaf(df, df, lsum);
    }
    out[VQ_ZQ + 1 + (size_t)r] = (float)bc;

#pragma unroll
    for (int off = 32; off > 0; off >>= 1)
        lsum += __shfl_down(lsum, off, 64);
    __shared__ float wsum[MAIN_BLOCK / 64];
    const int lane = threadIdx.x & 63;
    const int wid = threadIdx.x >> 6;
    if (lane == 0) wsum[wid] = lsum;
    __syncthreads();
    if (threadIdx.x == 0)
        partials[blockIdx.x] = (wsum[0] + wsum[1]) + (wsum[2] + wsum[3]);
}

__global__ void vq_final(const float* __restrict__ partials, float* __restrict__ out) {
    if (threadIdx.x == 0 && blockIdx.x == 0) {
        float s = 0.0f;
        for (int i = 0; i < MAIN_GRID; ++i) s += partials[i];
        const float mse = s / (float)VQ_ZQ;
        out[VQ_ZQ] = mse + 0.25f * mse;   /* vq_loss + 0.25*commitment */
    }
}

extern "C" void kernel_launch(void* const* d_in, const int* in_sizes, int n_in,
                              void* d_out, int out_size, void* d_ws, size_t ws_size,
                              hipStream_t stream) {
    const float* z   = (const float*)d_in[0];
    const float* emb = (const float*)d_in[1];
    float* out = (float*)d_out;
    float* nE = (float*)d_ws;                       /* 1024 f  @ 0      */
    float* partials = nE + VQ_N;                    /* 512 f   @ 4096B  */
    float2* cand = (float2*)(partials + MAIN_GRID); /* 4*R f2  @ 6144B  */

    vq_norme<<<dim3(VQ_N / 256), dim3(256), 0, stream>>>(emb, nE);
    vq_dist<<<dim3(MAIN_GRID, NSEG), dim3(MAIN_BLOCK), 0, stream>>>(z, emb, nE, cand);
    vq_epilogue<<<dim3(MAIN_GRID), dim3(MAIN_BLOCK), 0, stream>>>(z, emb, cand, out, partials);
    vq_final<<<dim3(1), dim3(64), 0, stream>>>(partials, out);
}

// Round 4
// 330.707 us; speedup vs baseline: 2.1296x; 1.0031x over previous
//
#include <hip/hip_runtime.h>

#define VQ_B 32
#define VQ_D 64
#define VQ_L 4096
#define VQ_N 1024
#define VQ_R (VQ_B * VQ_L)            /* 131072 rows */
#define VQ_ZQ ((size_t)VQ_R * VQ_D)   /* 8388608 z_q elements */
#define MAIN_BLOCK 256
#define MAIN_GRID (VQ_R / MAIN_BLOCK) /* 512 */
#define NSEG 4
#define SEG_C (VQ_N / NSEG)           /* 256 codes per segment */

typedef __attribute__((ext_vector_type(16))) float f32x16;

/* zv element i (0..63) out of four named 16-wide vector registers.
   All uses are after full unroll -> compile-time-constant subscripts. */
#define ZVE(i) ((i) < 16 ? zvA[(i) & 15] : (i) < 32 ? zvB[(i) & 15] \
               : (i) < 48 ? zvC[(i) & 15] : zvD[(i) & 15])

/* Opaque register barrier: the allocator may no longer rematerialize the
   z loads inside the code loop — values must stay VGPR-resident. */
#define PIN_ZV() asm volatile("" : "+v"(zvA), "+v"(zvB), "+v"(zvC), "+v"(zvD))

/* fl(x*x) rounded BEFORE any add (numpy elementwise temp; no fma fusion). */
#define SQB(x) ({ float s_ = (x) * (x); asm volatile("" : "+v"(s_)); s_; })

/* numpy pairwise_sum (n=64 contiguous) of squares:
   r[j] = sum_i v[8i+j]^2 sequentially, then ((r0+r1)+(r2+r3))+((r4+r5)+(r6+r7)). */
#define NP_PAIRWISE64_SQ(dst)                                                  \
    do {                                                                       \
        float r0 = SQB(ZVE(0)), r1 = SQB(ZVE(1)), r2 = SQB(ZVE(2)),            \
              r3 = SQB(ZVE(3)), r4 = SQB(ZVE(4)), r5 = SQB(ZVE(5)),            \
              r6 = SQB(ZVE(6)), r7 = SQB(ZVE(7));                              \
        _Pragma("unroll")                                                      \
        for (int i_ = 1; i_ < 8; ++i_) {                                       \
            r0 += SQB(ZVE(8 * i_ + 0)); r1 += SQB(ZVE(8 * i_ + 1));            \
            r2 += SQB(ZVE(8 * i_ + 2)); r3 += SQB(ZVE(8 * i_ + 3));            \
            r4 += SQB(ZVE(8 * i_ + 4)); r5 += SQB(ZVE(8 * i_ + 5));            \
            r6 += SQB(ZVE(8 * i_ + 6)); r7 += SQB(ZVE(8 * i_ + 7));            \
        }                                                                      \
        dst = ((r0 + r1) + (r2 + r3)) + ((r4 + r5) + (r6 + r7));               \
    } while (0)

__global__ void vq_norme(const float* __restrict__ emb, float* __restrict__ nE) {
    const int c = blockIdx.x * blockDim.x + threadIdx.x;
    if (c >= VQ_N) return;
    const float* ec = emb + (c << 6);
    f32x16 zvA, zvB, zvC, zvD;
#pragma unroll
    for (int d = 0; d < 16; ++d) {
        zvA[d] = ec[d];
        zvB[d] = ec[d + 16];
        zvC[d] = ec[d + 32];
        zvD[d] = ec[d + 48];
    }
    float s;
    NP_PAIRWISE64_SQ(s);
    nE[c] = s;
}

/* Segment distance kernel: blockIdx.y = code segment. Candidates to ws. */
__global__ __launch_bounds__(MAIN_BLOCK, 4) void vq_dist(
    const float* __restrict__ z, const float* __restrict__ emb,
    const float* __restrict__ nE, float2* __restrict__ cand)
{
    const int r = blockIdx.x * MAIN_BLOCK + threadIdx.x;
    const int seg = blockIdx.y;
    const int b = r >> 12;
    const int l = r & (VQ_L - 1);
    const float* zp = z + ((size_t)b << 18) + l;   /* z[b, d, l], stride L over d */

    f32x16 zvA, zvB, zvC, zvD;
#pragma unroll
    for (int d = 0; d < 16; ++d) {
        zvA[d] = zp[(size_t)d << 12];
        zvB[d] = zp[(size_t)(d + 16) << 12];
        zvC[d] = zp[(size_t)(d + 32) << 12];
        zvD[d] = zp[(size_t)(d + 48) << 12];
    }
    PIN_ZV();   /* forbid load-rematerialization across the code loop */

    float szz;
    NP_PAIRWISE64_SQ(szz);   /* bitwise identical across segments */

    const int c0 = seg * SEG_C;
    float best = __builtin_inff();
    int bc = c0;
#pragma unroll 2
    for (int cc = 0; cc < SEG_C; ++cc) {
        const int c = c0 + cc;
        const float* __restrict__ ec = emb + (c << 6);  /* wave-uniform -> s_load */
        float acc = 0.0f;
#pragma unroll
        for (int k = 0; k < VQ_D; ++k)
            acc = __builtin_fmaf(ZVE(k), ec[k], acc);   /* OpenBLAS sdot chain */
        const float dist = (szz - 2.0f * acc) + nE[c];
        if (dist < best) { best = dist; bc = c; }       /* strict <: first index */
    }
    cand[(size_t)seg * VQ_R + r] = make_float2(best, (float)bc);
}

/* Merge 4 candidates, gather, write z_q + codes, loss partials. */
__global__ __launch_bounds__(MAIN_BLOCK) void vq_epilogue(
    const float* __restrict__ z, const float* __restrict__ emb,
    const float2* __restrict__ cand, float* __restrict__ out,
    float* __restrict__ partials)
{
    const int r = blockIdx.x * MAIN_BLOCK + threadIdx.x;
    const int b = r >> 12;
    const int l = r & (VQ_L - 1);

    float best = __builtin_inff();
    int bc = 0;
#pragma unroll
    for (int seg = 0; seg < NSEG; ++seg) {              /* ascending: ties -> first */
        const float2 cd = cand[(size_t)seg * VQ_R + r];
        if (cd.x < best) { best = cd.x; bc = (int)cd.y; }
    }

    const float* zp = z + ((size_t)b << 18) + l;
    const float* __restrict__ eb = emb + (bc << 6);
    float lsum = 0.0f;
#pragma unroll
    for (int d = 0; d < VQ_D; ++d) {
        const float q = eb[d];
        const float zd = zp[(size_t)d << 12];
        out[((size_t)b << 18) + ((size_t)d << 12) + l] = q;
        const float df = q - zd;
        lsum = __builtin_fmaf(df, df, lsum);
    }
    out[VQ_ZQ + 1 + (size_t)r] = (float)bc;

#pragma unroll
    for (int off = 32; off > 0; off >>= 1)
        lsum += __shfl_down(lsum, off, 64);
    __shared__ float wsum[MAIN_BLOCK / 64];
    const int lane = threadIdx.x & 63;
    const int wid = threadIdx.x >> 6;
    if (lane == 0) wsum[wid] = lsum;
    __syncthreads();
    if (threadIdx.x == 0)
        partials[blockIdx.x] = (wsum[0] + wsum[1]) + (wsum[2] + wsum[3]);
}

__global__ void vq_final(const float* __restrict__ partials, float* __restrict__ out) {
    if (threadIdx.x == 0 && blockIdx.x == 0) {
        float s = 0.0f;
        for (int i = 0; i < MAIN_GRID; ++i) s += partials[i];
        const float mse = s / (float)VQ_ZQ;
        out[VQ_ZQ] = mse + 0.25f * mse;   /* vq_loss + 0.25*commitment */
    }
}

extern "C" void kernel_launch(void* const* d_in, const int* in_sizes, int n_in,
                              void* d_out, int out_size, void* d_ws, size_t ws_size,
                              hipStream_t stream) {
    const float* z   = (const float*)d_in[0];
    const float* emb = (const float*)d_in[1];
    float* out = (float*)d_out;
    float* nE = (float*)d_ws;                       /* 1024 f  @ 0      */
    float* partials = nE + VQ_N;                    /* 512 f   @ 4096B  */
    float2* cand = (float2*)(partials + MAIN_GRID); /* 4*R f2  @ 6144B  */

    vq_norme<<<dim3(VQ_N / 256), dim3(256), 0, stream>>>(emb, nE);
    vq_dist<<<dim3(MAIN_GRID, NSEG), dim3(MAIN_BLOCK), 0, stream>>>(z, emb, nE, cand);
    vq_epilogue<<<dim3(MAIN_GRID), dim3(MAIN_BLOCK), 0, stream>>>(z, emb, cand, out, partials);
    vq_final<<<dim3(1), dim3(64), 0, stream>>>(partials, out);
}